// Round 1
// baseline (609.271 us; speedup 1.0000x reference)
//
#include <hip/hip_runtime.h>

// AngularTensorProduct: out[e,r,l3,c] = sum_k pf[k] * a1[e,r,l1[k],c] * a2[e,r,l2[k],c]
// MAX_L=3 -> A=20 angular monomials, K=84 combos. Tensors [E,R,A,C] f32,
// E=100000 R=8 C=16. Pure streaming (each element touched once) -> memory-bound.
// Combo table is deterministic from MAX_L; regenerated here as constexpr so the
// fully-unrolled inner loop uses compile-time register indices (no scratch).

#define NA 20
#define NK 84

namespace atp {

// index of monomial (x,y,z) in the nested-loop l_list order
constexpr int lidx(int x, int y, int z) {
  int i = 0;
  for (int a = 0; a < x; ++a) i += (4 - a) * (5 - a) / 2;  // T(3-a) pairs
  for (int b = 0; b < y; ++b) i += 4 - x - b;
  return i + z;
}

constexpr int combi(int n, int k) {
  int r = 1;
  for (int i = 1; i <= k; ++i) r = r * (n - k + i) / i;
  return r;
}

struct Tab {
  int l1[NK];
  int l2[NK];
  float pf[NK];
  int cnt[NA];
  int off[NA];
};

constexpr Tab make_tab() {
  Tab t{};
  int n = 0, m = 0;
  for (int x = 0; x <= 3; ++x)
    for (int y = 0; y <= 3 - x; ++y)
      for (int z = 0; z <= 3 - x - y; ++z) {
        t.off[m] = n;
        t.cnt[m] = (x + 1) * (y + 1) * (z + 1);
        for (int a = 0; a <= x; ++a)
          for (int b = 0; b <= y; ++b)
            for (int c = 0; c <= z; ++c) {
              t.l1[n] = lidx(a, b, c);
              t.l2[n] = lidx(x - a, y - b, z - c);
              t.pf[n] = (float)(combi(x, a) * combi(y, b) * combi(z, c));
              ++n;
            }
        ++m;
      }
  return t;
}

constexpr Tab T = make_tab();

}  // namespace atp

// One thread = one (e,r) row x one float2 channel pair.
// Loads 20 float2 from each input (stride 16 floats), computes 84 fused terms,
// writes each l3 accumulator as soon as its (contiguous) combo range is done
// -> only 1 live accumulator; ~90 VGPRs total.
__global__ __launch_bounds__(256) void atp_kernel(
    const float* __restrict__ in1, const float* __restrict__ in2,
    float* __restrict__ out, int n_pairs) {
  const int tid = blockIdx.x * 256 + threadIdx.x;
  if (tid >= n_pairs) return;
  const int er = tid >> 3;  // (e*R + r), 8 float2 pairs per row
  const int c2 = tid & 7;   // which float2 within the 16 channels

  const float2* p1 = reinterpret_cast<const float2*>(in1) + er * (NA * 8) + c2;
  const float2* p2 = reinterpret_cast<const float2*>(in2) + er * (NA * 8) + c2;
  float2* po = reinterpret_cast<float2*>(out) + er * (NA * 8) + c2;

  float2 v1[NA], v2[NA];
#pragma unroll
  for (int a = 0; a < NA; ++a) v1[a] = p1[a * 8];
#pragma unroll
  for (int a = 0; a < NA; ++a) v2[a] = p2[a * 8];

#pragma unroll
  for (int i3 = 0; i3 < NA; ++i3) {
    float2 acc = make_float2(0.f, 0.f);
#pragma unroll
    for (int j = 0; j < atp::T.cnt[i3]; ++j) {
      const int k = atp::T.off[i3] + j;        // compile-time after unroll
      const float pf = atp::T.pf[k];
      const float2 a = v1[atp::T.l1[k]];       // constant register indices
      const float2 b = v2[atp::T.l2[k]];
      acc.x = fmaf(pf * a.x, b.x, acc.x);
      acc.y = fmaf(pf * a.y, b.y, acc.y);
    }
    po[i3 * 8] = acc;
  }
}

extern "C" void kernel_launch(void* const* d_in, const int* in_sizes, int n_in,
                              void* d_out, int out_size, void* d_ws, size_t ws_size,
                              hipStream_t stream) {
  const float* in1 = (const float*)d_in[0];
  const float* in2 = (const float*)d_in[1];
  float* out = (float*)d_out;
  // out_size = E*R*A*C; threads = E*R*C/2 (one float2 per thread)
  const int n_pairs = out_size / NA / 2;
  const int blocks = (n_pairs + 255) / 256;
  atp_kernel<<<blocks, 256, 0, stream>>>(in1, in2, out, n_pairs);
}

// Round 3
// 601.409 us; speedup vs baseline: 1.0131x; 1.0131x over previous
//
#include <hip/hip_runtime.h>

// AngularTensorProduct: out[e,r,l3,c] = sum_k pf[k] * a1[e,r,l1[k],c] * a2[e,r,l2[k],c]
// MAX_L=3 -> A=20 angular monomials, K=84 combos. Tensors [E,R,A,C] f32,
// E=100000 R=8 C=16. Memory-bound streaming (compulsory 3.07 GB -> 488 us floor
// at 6.3 TB/s). R1: float2 version hit 647 us (4.75 TB/s effective).
// R2/R3: float4 loads (16 B/lane sweet spot, 1 KiB/wave-instruction) +
// nontemporal stores via native ext_vector_type (HIP float4 rejected by the
// builtin). Output is never re-read -> skip write-allocate pollution.

#define NA 20
#define NK 84

typedef float f32x4 __attribute__((ext_vector_type(4)));

namespace atp {

// index of monomial (x,y,z) in the nested-loop l_list order
constexpr int lidx(int x, int y, int z) {
  int i = 0;
  for (int a = 0; a < x; ++a) i += (4 - a) * (5 - a) / 2;
  for (int b = 0; b < y; ++b) i += 4 - x - b;
  return i + z;
}

constexpr int combi(int n, int k) {
  int r = 1;
  for (int i = 1; i <= k; ++i) r = r * (n - k + i) / i;
  return r;
}

struct Tab {
  int l1[NK];
  int l2[NK];
  float pf[NK];
  int cnt[NA];
  int off[NA];
};

constexpr Tab make_tab() {
  Tab t{};
  int n = 0, m = 0;
  for (int x = 0; x <= 3; ++x)
    for (int y = 0; y <= 3 - x; ++y)
      for (int z = 0; z <= 3 - x - y; ++z) {
        t.off[m] = n;
        t.cnt[m] = (x + 1) * (y + 1) * (z + 1);
        for (int a = 0; a <= x; ++a)
          for (int b = 0; b <= y; ++b)
            for (int c = 0; c <= z; ++c) {
              t.l1[n] = lidx(a, b, c);
              t.l2[n] = lidx(x - a, y - b, z - c);
              t.pf[n] = (float)(combi(x, a) * combi(y, b) * combi(z, c));
              ++n;
            }
        ++m;
      }
  return t;
}

constexpr Tab T = make_tab();

}  // namespace atp

// One thread = one (e,r) row x one float4 (4 of 16 channels).
// 4 consecutive lanes cover 64 B contiguous; a wave covers 16 rows -> 1 KiB
// per global_load_dwordx4. Fully-unrolled combo loop with compile-time
// register indices (rule #20); write-as-you-go keeps 1 live accumulator.
__global__ __launch_bounds__(256) void atp_kernel(
    const float* __restrict__ in1, const float* __restrict__ in2,
    float* __restrict__ out, int n_quads) {
  const int tid = blockIdx.x * 256 + threadIdx.x;
  if (tid >= n_quads) return;
  const int er = tid >> 2;  // (e*R + r), 4 float4 quads per row
  const int c4 = tid & 3;   // which float4 within the 16 channels

  const f32x4* p1 = reinterpret_cast<const f32x4*>(in1) + er * (NA * 4) + c4;
  const f32x4* p2 = reinterpret_cast<const f32x4*>(in2) + er * (NA * 4) + c4;
  f32x4* po = reinterpret_cast<f32x4*>(out) + er * (NA * 4) + c4;

  f32x4 v1[NA], v2[NA];
#pragma unroll
  for (int a = 0; a < NA; ++a) v1[a] = p1[a * 4];
#pragma unroll
  for (int a = 0; a < NA; ++a) v2[a] = p2[a * 4];

#pragma unroll
  for (int i3 = 0; i3 < NA; ++i3) {
    f32x4 acc = (f32x4)(0.f);
#pragma unroll
    for (int j = 0; j < atp::T.cnt[i3]; ++j) {
      const int k = atp::T.off[i3] + j;        // compile-time after unroll
      const float pf = atp::T.pf[k];
      const f32x4 a = v1[atp::T.l1[k]];        // constant register indices
      const f32x4 b = v2[atp::T.l2[k]];
      acc.x = fmaf(pf * a.x, b.x, acc.x);
      acc.y = fmaf(pf * a.y, b.y, acc.y);
      acc.z = fmaf(pf * a.z, b.z, acc.z);
      acc.w = fmaf(pf * a.w, b.w, acc.w);
    }
    __builtin_nontemporal_store(acc, po + i3 * 4);
  }
}

extern "C" void kernel_launch(void* const* d_in, const int* in_sizes, int n_in,
                              void* d_out, int out_size, void* d_ws, size_t ws_size,
                              hipStream_t stream) {
  const float* in1 = (const float*)d_in[0];
  const float* in2 = (const float*)d_in[1];
  float* out = (float*)d_out;
  // out_size = E*R*A*C; threads = E*R*C/4 (one float4 per thread)
  const int n_quads = out_size / NA / 4;
  const int blocks = (n_quads + 255) / 256;
  atp_kernel<<<blocks, 256, 0, stream>>>(in1, in2, out, n_quads);
}

// Round 4
// 578.365 us; speedup vs baseline: 1.0534x; 1.0398x over previous
//
#include <hip/hip_runtime.h>

// AngularTensorProduct: out[e,r,l3,c] = sum_k pf[k] * a1[e,r,l1[k],c] * a2[e,r,l2[k],c]
// MAX_L=3 -> A=20 monomials, K=84 combos. [E,R,A,C] f32, E=100000 R=8 C=16.
// Memory-bound: compulsory 3.07 GB -> 488 us floor at 6.3 TB/s copy ceiling.
// R1 (float2 gather): 609 us. R3 (float4 gather + NT stores): 601 us, but NT
// stores cost +12.5% WRITE (partial 128B-line eviction) -> reverted.
// R4: LDS-staged linear version — global access is made bit-identical to a
// 3-stream copy (1 KiB/wave dense segments, the m13 6.29 TB/s pattern).
// Per-row gather/scatter moves to LDS (padded stride 328 f32 -> uniform 2-way
// bank access = free per m136). This is the ceiling probe: if it doesn't beat
// ~600 us, the scattered-segment theory is wrong and 5.1 TB/s is the op ceiling.

#define NA 20
#define NK 84
#define TR 8      // rows (e,r) per tile
#define ROWQ 80   // float4 per row (A*C = 320 f32)
#define PADQ 82   // padded row stride in float4 (328 f32; 328%32==8 -> 2-way banks)
#define NTH 128   // threads per block = TR*16 channel tasks

typedef float f32x4 __attribute__((ext_vector_type(4)));

namespace atp {

constexpr int lidx(int x, int y, int z) {
  int i = 0;
  for (int a = 0; a < x; ++a) i += (4 - a) * (5 - a) / 2;
  for (int b = 0; b < y; ++b) i += 4 - x - b;
  return i + z;
}

constexpr int combi(int n, int k) {
  int r = 1;
  for (int i = 1; i <= k; ++i) r = r * (n - k + i) / i;
  return r;
}

struct Tab {
  int l1[NK];
  int l2[NK];
  float pf[NK];
  int cnt[NA];
  int off[NA];
};

constexpr Tab make_tab() {
  Tab t{};
  int n = 0, m = 0;
  for (int x = 0; x <= 3; ++x)
    for (int y = 0; y <= 3 - x; ++y)
      for (int z = 0; z <= 3 - x - y; ++z) {
        t.off[m] = n;
        t.cnt[m] = (x + 1) * (y + 1) * (z + 1);
        for (int a = 0; a <= x; ++a)
          for (int b = 0; b <= y; ++b)
            for (int c = 0; c <= z; ++c) {
              t.l1[n] = lidx(a, b, c);
              t.l2[n] = lidx(x - a, y - b, z - c);
              t.pf[n] = (float)(combi(x, a) * combi(y, b) * combi(z, c));
              ++n;
            }
        ++m;
      }
  return t;
}

constexpr Tab T = make_tab();

}  // namespace atp

// Block = 128 threads = one 8-row tile (8*1280 B per tensor).
// Phase 1: stage both input tiles, fully linear (5 dwordx4/thread/tensor).
// Phase 2: thread (row, c) pulls 20+20 scalars from padded LDS (2-way banks),
//          computes 20 outputs in registers (compile-time indices, rule #20).
// Phase 3: scatter outputs back into lds1 (reused), then linear store.
// LDS = 2 * 8*328*4 B = 20.5 KB -> 7 blocks/CU, 14 waves/CU.
__global__ __launch_bounds__(NTH) void atp_kernel(
    const float* __restrict__ in1, const float* __restrict__ in2,
    float* __restrict__ out) {
  __shared__ f32x4 lds1[TR * PADQ];
  __shared__ f32x4 lds2[TR * PADQ];

  const int t = threadIdx.x;
  const long base_q = (long)blockIdx.x * (TR * ROWQ);  // float4 index
  const f32x4* g1 = reinterpret_cast<const f32x4*>(in1) + base_q;
  const f32x4* g2 = reinterpret_cast<const f32x4*>(in2) + base_q;
  f32x4* go = reinterpret_cast<f32x4*>(out) + base_q;

  // ---- phase 1: linear global -> padded LDS ----
#pragma unroll
  for (int k = 0; k < 5; ++k) {
    const int q = k * NTH + t;      // 0..639
    const int row = q / ROWQ;
    const int qq = q - row * ROWQ;
    lds1[row * PADQ + qq] = g1[q];
    lds2[row * PADQ + qq] = g2[q];
  }
  __syncthreads();

  // ---- phase 2: per-(row,c) compute from LDS ----
  const int row = t >> 4;
  const int c = t & 15;
  const float* l1p = reinterpret_cast<const float*>(lds1) + row * (PADQ * 4) + c;
  const float* l2p = reinterpret_cast<const float*>(lds2) + row * (PADQ * 4) + c;

  float v1[NA], v2[NA], o[NA];
#pragma unroll
  for (int a = 0; a < NA; ++a) v1[a] = l1p[a * 16];
#pragma unroll
  for (int a = 0; a < NA; ++a) v2[a] = l2p[a * 16];

#pragma unroll
  for (int i3 = 0; i3 < NA; ++i3) {
    float acc = 0.f;
#pragma unroll
    for (int j = 0; j < atp::T.cnt[i3]; ++j) {
      const int k = atp::T.off[i3] + j;               // compile-time
      acc = fmaf(atp::T.pf[k] * v1[atp::T.l1[k]], v2[atp::T.l2[k]], acc);
    }
    o[i3] = acc;
  }
  __syncthreads();  // all LDS reads done; lds1 reusable for output

  // ---- phase 3: scatter to LDS, then linear store ----
  float* lop = reinterpret_cast<float*>(lds1) + row * (PADQ * 4) + c;
#pragma unroll
  for (int a = 0; a < NA; ++a) lop[a * 16] = o[a];
  __syncthreads();

#pragma unroll
  for (int k = 0; k < 5; ++k) {
    const int q = k * NTH + t;
    const int row2 = q / ROWQ;
    const int qq = q - row2 * ROWQ;
    go[q] = lds1[row2 * PADQ + qq];
  }
}

extern "C" void kernel_launch(void* const* d_in, const int* in_sizes, int n_in,
                              void* d_out, int out_size, void* d_ws, size_t ws_size,
                              hipStream_t stream) {
  const float* in1 = (const float*)d_in[0];
  const float* in2 = (const float*)d_in[1];
  float* out = (float*)d_out;
  // out_size = E*R*A*C f32; tiles of TR rows of A*C floats each
  const int n_tiles = out_size / (TR * NA * 16);  // = 100000
  atp_kernel<<<n_tiles, NTH, 0, stream>>>(in1, in2, out);
}

// Round 5
// 541.512 us; speedup vs baseline: 1.1251x; 1.0681x over previous
//
#include <hip/hip_runtime.h>

// AngularTensorProduct: out[e,r,l3,c] = sum_k pf[k] * a1[e,r,l1[k],c] * a2[e,r,l2[k],c]
// MAX_L=3 -> A=20 monomials, K=84 combos. [E,R,A,C] f32, E=100000 R=8 C=16.
// Memory-bound: compulsory 3.07 GB; float4-copy ceiling 6.29 TB/s -> 488 us floor.
// History: R1 float2-gather 609 us; R3 float4-gather+NT-stores 601 (NT inflated
// WRITE +12.5% -> cached stores only); R4 full LDS-staged dense streams 578 us
// = 5.31 TB/s = 84.5% of copy BW (the measured 82-86% band for R+W streaming).
// R5: delete the output LDS restage (phase 3/4) — R1 proved scattered CACHED
// stores merge to exact compulsory WRITE traffic in L2. Stores now interleave
// with the FMA chain (write-as-you-go), removing ~350 LDS-pipe cycles + 2
// syncthreads from each wave's critical path. If this is within ±2% of R4,
// the mixed-stream band is the ceiling -> roofline.

#define NA 20
#define NK 84
#define TR 8      // rows (e,r) per tile
#define ROWQ 80   // float4 per row (A*C = 320 f32)
#define PADQ 82   // padded row stride in float4 (328 f32; 328%32==8 -> 2-way banks, free per m136)
#define NTH 128   // threads per block = TR*16 channel tasks

typedef float f32x4 __attribute__((ext_vector_type(4)));

namespace atp {

// index of monomial (x,y,z) in the nested-loop l_list order
constexpr int lidx(int x, int y, int z) {
  int i = 0;
  for (int a = 0; a < x; ++a) i += (4 - a) * (5 - a) / 2;
  for (int b = 0; b < y; ++b) i += 4 - x - b;
  return i + z;
}

constexpr int combi(int n, int k) {
  int r = 1;
  for (int i = 1; i <= k; ++i) r = r * (n - k + i) / i;
  return r;
}

struct Tab {
  int l1[NK];
  int l2[NK];
  float pf[NK];
  int cnt[NA];
  int off[NA];
};

constexpr Tab make_tab() {
  Tab t{};
  int n = 0, m = 0;
  for (int x = 0; x <= 3; ++x)
    for (int y = 0; y <= 3 - x; ++y)
      for (int z = 0; z <= 3 - x - y; ++z) {
        t.off[m] = n;
        t.cnt[m] = (x + 1) * (y + 1) * (z + 1);
        for (int a = 0; a <= x; ++a)
          for (int b = 0; b <= y; ++b)
            for (int c = 0; c <= z; ++c) {
              t.l1[n] = lidx(a, b, c);
              t.l2[n] = lidx(x - a, y - b, z - c);
              t.pf[n] = (float)(combi(x, a) * combi(y, b) * combi(z, c));
              ++n;
            }
        ++m;
      }
  return t;
}

constexpr Tab T = make_tab();

}  // namespace atp

// Block = 128 threads = one 8-row tile (8*1280 B per tensor).
// Phase 1: stage both input tiles linearly into padded LDS (dense 1 KiB/wave
//          global segments — the m13 copy pattern).
// Phase 2: thread (row, c) gathers 20+20 scalars from LDS (2-way banks = free),
//          computes each of the 20 l3 outputs with compile-time register
//          indices (rule #20) and stores it DIRECTLY to global, interleaved
//          with the FMA chain. Scattered 4B cached stores merge to full lines
//          in L2 (R1: WRITE_SIZE exactly compulsory).
__global__ __launch_bounds__(NTH) void atp_kernel(
    const float* __restrict__ in1, const float* __restrict__ in2,
    float* __restrict__ out) {
  __shared__ f32x4 lds1[TR * PADQ];
  __shared__ f32x4 lds2[TR * PADQ];

  const int t = threadIdx.x;
  const long base_q = (long)blockIdx.x * (TR * ROWQ);  // float4 index
  const f32x4* g1 = reinterpret_cast<const f32x4*>(in1) + base_q;
  const f32x4* g2 = reinterpret_cast<const f32x4*>(in2) + base_q;

  // ---- phase 1: linear global -> padded LDS ----
#pragma unroll
  for (int k = 0; k < 5; ++k) {
    const int q = k * NTH + t;      // 0..639
    const int row = q / ROWQ;
    const int qq = q - row * ROWQ;
    lds1[row * PADQ + qq] = g1[q];
    lds2[row * PADQ + qq] = g2[q];
  }
  __syncthreads();

  // ---- phase 2: per-(row,c) compute from LDS, direct global stores ----
  const int row = t >> 4;
  const int c = t & 15;
  const float* l1p = reinterpret_cast<const float*>(lds1) + row * (PADQ * 4) + c;
  const float* l2p = reinterpret_cast<const float*>(lds2) + row * (PADQ * 4) + c;
  float* op = out + base_q * 4 + row * (ROWQ * 4) + c;

  float v1[NA], v2[NA];
#pragma unroll
  for (int a = 0; a < NA; ++a) v1[a] = l1p[a * 16];
#pragma unroll
  for (int a = 0; a < NA; ++a) v2[a] = l2p[a * 16];

#pragma unroll
  for (int i3 = 0; i3 < NA; ++i3) {
    float acc = 0.f;
#pragma unroll
    for (int j = 0; j < atp::T.cnt[i3]; ++j) {
      const int k = atp::T.off[i3] + j;               // compile-time
      acc = fmaf(atp::T.pf[k] * v1[atp::T.l1[k]], v2[atp::T.l2[k]], acc);
    }
    op[i3 * 16] = acc;   // cached scalar store; L2 merges to full lines
  }
}

extern "C" void kernel_launch(void* const* d_in, const int* in_sizes, int n_in,
                              void* d_out, int out_size, void* d_ws, size_t ws_size,
                              hipStream_t stream) {
  const float* in1 = (const float*)d_in[0];
  const float* in2 = (const float*)d_in[1];
  float* out = (float*)d_out;
  // out_size = E*R*A*C f32; tiles of TR rows of A*C floats each
  const int n_tiles = out_size / (TR * NA * 16);  // = 100000
  atp_kernel<<<n_tiles, NTH, 0, stream>>>(in1, in2, out);
}